// Round 2
// baseline (132324.048 us; speedup 1.0000x reference)
//
#include <hip/hip_runtime.h>
#include <math.h>

typedef float v4 __attribute__((ext_vector_type(4)));
typedef unsigned long long u64;

static constexpr int B_ = 32;
static constexpr int S_ = 2048;
static constexpr int E_ = 512;
static constexpr int V_ = 32000;
static constexpr float EPS_ = 1e-6f;
static constexpr int NH_ = 8;     // blocks (column slices) per batch
static constexpr int CH_ = 64;    // columns per block
static constexpr int REC_ = 96;   // floats per slice record (384B, line-aligned)

// ---------------------------------------------------------------------------
// K1: 8-blocks-per-batch scan, 256 blocks x 1024 threads (1 block/CU).
//
// Exchange protocol (NEW): flag-gated bulk transfer.
//   producer (wave h): 64 zmid values + S,Q stats as PLAIN coalesced stores
//   (3 cache lines) -> s_waitcnt vmcnt(0) -> ONE tagged u64 flag store with
//   RELEASE/AGENT. Consumers (waves 8..15, one per foreign slice): spin on
//   the flag with ACQUIRE/AGENT loads (emits buffer_inv -> L1 fresh), then
//   PLAIN coalesced loads of the record. ~10 L2 transactions per block-step
//   instead of ~500 uncoalesced atomics.
//
// Intra-block schedule (NEW): ONE __syncthreads per step.
//   * z is register-resident: thread i holds z_i. Matvec: thread (wv,lane)
//     owns column lane, rows wv*64..+63; z broadcast via v_readlane
//     (VALU pipe, compile-time lane) -> zero DS ops, zero bank conflicts.
//   * waves 0..7 write 8 per-column partials to part[8][64], bump an LDS
//     counter; wave h (owner of columns c0..c0+63 AND z rows c0..c0+63)
//     spins on the counter, finishes zmid, publishes. Publish is never
//     behind a block barrier -> deadlock-free by construction.
//   * pollers start at step begin, overlapping matvec+publish entirely.
//   * LN->z-update->next matvec is intra-wave (wave w owns z rows w*64..+63
//     and reads exactly those rows) -> no second barrier.
// Double-buffered by step parity; monotone tags kill stale/replay reads.
// ---------------------------------------------------------------------------
__global__ __launch_bounds__(1024) void scan8w(
    const int* __restrict__ seq,     // (B,S)
    const float* __restrict__ emb,   // (V,E)
    const float* __restrict__ Wdec,  // (E,E) row-major
    const float* __restrict__ bdec,  // (E)
    const float* __restrict__ gamma, // (E)
    const float* __restrict__ beta,  // (E)
    float* __restrict__ zout,        // (B,E)
    float* __restrict__ vbuf,        // (B,2,NH,REC) slice records
    u64* __restrict__ flg)           // (B,2,NH) tagged flags (ws, zeroed)
{
    __shared__ float part[NH_][CH_];   // matvec partials (8 per column)
    __shared__ float zmbuf[2][E_];     // gathered zmid, parity dbuf
    __shared__ float sst[2][NH_][2];   // per-slice (S,Q), parity dbuf
    __shared__ int   seq_l[S_];
    __shared__ unsigned cnt;           // monotone partial counter

    const int bid  = blockIdx.x;
    const int b    = bid & 31;    // batch
    const int h    = bid >> 5;    // slice 0..7
    const int c0   = h * CH_;
    const int tid  = threadIdx.x;
    const int wv   = tid >> 6;    // 16 waves
    const int lane = tid & 63;
    const bool comp = (wv < NH_); // waves 0..7 compute, 8..15 poll

    // --- W: thread (wv,lane) holds W[wv*64+q][c0+lane], q=0..63 (64 VGPRs)
    float w[64];
    if (comp) {
        const float* wp = Wdec + (size_t)(wv * 64) * E_ + c0 + lane;
        #pragma unroll
        for (int q = 0; q < 64; ++q) w[q] = wp[(size_t)q * E_];
    }

    const int* seqb = seq + (size_t)b * S_;
    for (int i = tid; i < S_; i += 1024) seq_l[i] = seqb[i];

    const float gmm = comp ? gamma[tid] : 0.f;
    const float btt = comp ? beta[tid] : 0.f;
    const float bd  = (wv == h) ? bdec[c0 + lane] : 0.f;
    const float sqrtE = 22.62741699796952f;   // sqrt(512)

    float* vb_b = vbuf + (size_t)b * 2 * NH_ * REC_;
    u64*   fg_b = flg  + (size_t)b * 2 * NH_;

    if (tid == 0) cnt = 0u;
    __syncthreads();

    // z_0 register-resident: thread tid holds z[tid]
    float zr = 0.f;
    if (comp) zr = emb[(size_t)seq_l[0] * E_ + tid] * sqrtE;

    for (int t = 0; t < S_; ++t) {
        const int p = t & 1;
        const u64 tag = (u64)(t + 1);

        // prefetch next embedding row (consumed at step end, hidden latency)
        float e = 0.f;
        if (comp) {
            const int tn = seq_l[(t + 1 < S_) ? t + 1 : t];
            e = emb[(size_t)tn * E_ + tid];
        }

        if (comp) {
            // --- matvec: 64 rows (own wave's z) x own column, VALU-only ---
            float acc = 0.f;
            #pragma unroll
            for (int q = 0; q < 64; ++q) {
                const float zq = __int_as_float(
                    __builtin_amdgcn_readlane(__float_as_int(zr), q));
                acc = fmaf(zq, w[q], acc);
            }
            part[wv][lane] = acc;
            asm volatile("s_waitcnt lgkmcnt(0)" ::: "memory");
            if (lane == 0)
                __hip_atomic_fetch_add(&cnt, 1u, __ATOMIC_RELAXED,
                                       __HIP_MEMORY_SCOPE_WORKGROUP);

            if (wv == h) {
                // wait for all 8 partial rows (LDS mini-sync, not a barrier)
                const unsigned tgt = 8u * (unsigned)(t + 1);
                while (__hip_atomic_load(&cnt, __ATOMIC_ACQUIRE,
                                         __HIP_MEMORY_SCOPE_WORKGROUP) < tgt) {}
                const float s01 = part[0][lane] + part[1][lane];
                const float s23 = part[2][lane] + part[3][lane];
                const float s45 = part[4][lane] + part[5][lane];
                const float s67 = part[6][lane] + part[7][lane];
                // zr here IS z[c0+lane] (wave h owns exactly these rows)
                const float zmid = zr + ((s01 + s23) + (s45 + s67)) + bd;

                float* vp = vb_b + (size_t)(p * NH_ + h) * REC_;
                vp[lane] = zmid;               // coalesced 256B, flies during stats
                // per-slice LN stats (single-wave butterfly, 12 DS ops total)
                float s = zmid, q2 = zmid * zmid;
                #pragma unroll
                for (int m = 1; m < 64; m <<= 1) {
                    s  += __shfl_xor(s, m);
                    q2 += __shfl_xor(q2, m);
                }
                if (lane == 0) { vp[64] = s; vp[65] = q2; }
                zmbuf[p][c0 + lane] = zmid;    // own slice -> LDS directly
                if (lane == 0) { sst[p][h][0] = s; sst[p][h][1] = q2; }
                // drain value/stat stores, then release the flag
                asm volatile("s_waitcnt vmcnt(0)" ::: "memory");
                if (lane == 0)
                    __hip_atomic_store(&fg_b[p * NH_ + h], tag,
                                       __ATOMIC_RELEASE, __HIP_MEMORY_SCOPE_AGENT);
            }
        } else {
            // --- pollers: wave 8+i gathers slice i (skip own slice) ---
            const int i = wv - 8;
            if (i != h) {
                const u64* fp = &fg_b[p * NH_ + i];
                while (__hip_atomic_load(fp, __ATOMIC_ACQUIRE,
                                         __HIP_MEMORY_SCOPE_AGENT) != tag) {}
                // acquire saw the tag -> buffer_inv done -> plain loads fresh
                const float* vp = vb_b + (size_t)(p * NH_ + i) * REC_;
                zmbuf[p][i * CH_ + lane] = vp[lane];
                if (lane < 2) sst[p][i][lane] = vp[64 + lane];
            }
        }
        __syncthreads();   // the ONE barrier: zmbuf/sst(p) complete

        if (comp) {
            // LN from broadcast LDS stats (fixed order -> bitwise-identical
            // across the 8 replica blocks of this batch)
            const float St =
                ((sst[p][0][0] + sst[p][1][0]) + (sst[p][2][0] + sst[p][3][0]))
              + ((sst[p][4][0] + sst[p][5][0]) + (sst[p][6][0] + sst[p][7][0]));
            const float Qt =
                ((sst[p][0][1] + sst[p][1][1]) + (sst[p][2][1] + sst[p][3][1]))
              + ((sst[p][4][1] + sst[p][5][1]) + (sst[p][6][1] + sst[p][7][1]));
            const float mu   = St * (1.0f / E_);
            const float var  = (Qt - St * mu) * (1.0f / (E_ - 1));
            const float invd = 1.0f / (sqrtf(var) + EPS_);
            const float zl   = gmm * (zmbuf[p][tid] - mu) * invd + btt;
            if (t == S_ - 1) {
                if (h == 0) zout[(size_t)b * E_ + tid] = zl;
            } else {
                zr = fmaf(e, sqrtE, zl);   // intra-wave: next matvec reads
            }                              // only this wave's zr lanes
        }
    }
}

// ---------------------------------------------------------------------------
// K2: y = z @ W_voc + b_voc. 250 blocks x 512 threads; each thread owns one
// vocab column for 8 batches (bg group). z reads are thread-uniform ->
// scalar-cache loads; W_voc streamed once (same cols across bg reuse L1).
// ---------------------------------------------------------------------------
__global__ __launch_bounds__(512) void logits_k(
    const float* __restrict__ zfin,  // (B,E)
    const float* __restrict__ Wvoc,  // (E,V)
    const float* __restrict__ bvoc,  // (V)
    float* __restrict__ y)           // (B,V)
{
    const int tid = threadIdx.x;
    const int col = blockIdx.x * 128 + (tid & 127);
    const int bg  = (tid >> 7) * 8;           // 0,8,16,24

    float acc[8] = {0.f, 0.f, 0.f, 0.f, 0.f, 0.f, 0.f, 0.f};
    const float* wp = Wvoc + col;
    const float* zp = zfin + (size_t)bg * E_;

    for (int k = 0; k < E_; k += 4) {
        const float w0 = wp[(size_t)(k + 0) * V_];
        const float w1 = wp[(size_t)(k + 1) * V_];
        const float w2 = wp[(size_t)(k + 2) * V_];
        const float w3 = wp[(size_t)(k + 3) * V_];
        #pragma unroll
        for (int g = 0; g < 8; ++g) {
            acc[g] = fmaf(zp[g * E_ + k + 0], w0, acc[g]);
            acc[g] = fmaf(zp[g * E_ + k + 1], w1, acc[g]);
            acc[g] = fmaf(zp[g * E_ + k + 2], w2, acc[g]);
            acc[g] = fmaf(zp[g * E_ + k + 3], w3, acc[g]);
        }
    }
    const float bv = bvoc[col];
    #pragma unroll
    for (int g = 0; g < 8; ++g)
        y[(size_t)(bg + g) * V_ + col] = acc[g] + bv;
}

// ---------------------------------------------------------------------------
// K3: per-batch log-sum-exp (bias already folded into y)
// ---------------------------------------------------------------------------
__global__ __launch_bounds__(1024) void lse_k(
    const float* __restrict__ y, float* __restrict__ corr)
{
    __shared__ float redm[16], redl[16];
    const int b = blockIdx.x;
    const int tid = threadIdx.x;
    const float* row = y + (size_t)b * V_;

    float m = -3.0e38f, l = 0.f;
    for (int v = tid; v < V_; v += 1024) {
        const float x = row[v];
        const float nm = fmaxf(m, x);
        l = l * __expf(m - nm) + __expf(x - nm);
        m = nm;
    }
    #pragma unroll
    for (int off = 32; off > 0; off >>= 1) {
        const float om = __shfl_down(m, off);
        const float ol = __shfl_down(l, off);
        const float nm = fmaxf(m, om);
        l = l * __expf(m - nm) + ol * __expf(om - nm);
        m = nm;
    }
    const int lane = tid & 63, wvv = tid >> 6;
    if (lane == 0) { redm[wvv] = m; redl[wvv] = l; }
    __syncthreads();
    if (tid == 0) {
        float M = redm[0], L = redl[0];
        for (int k = 1; k < 16; ++k) {
            const float nm = fmaxf(M, redm[k]);
            L = L * __expf(M - nm) + redl[k] * __expf(redm[k] - nm);
            M = nm;
        }
        corr[b] = M + logf(L);
    }
}

// ---------------------------------------------------------------------------
// K4: y -= corr[b]
// ---------------------------------------------------------------------------
__global__ __launch_bounds__(256) void fix_k(
    float* __restrict__ y, const float* __restrict__ corr)
{
    const int idx = blockIdx.x * 256 + threadIdx.x;   // float4 index
    const size_t o = (size_t)idx * 4;
    const int b = (int)(o / V_);
    const float cr = corr[b];
    v4 v = *(v4*)(y + o);
    v = v - cr;
    *(v4*)(y + o) = v;
}

// ---------------------------------------------------------------------------
extern "C" void kernel_launch(void* const* d_in, const int* in_sizes, int n_in,
                              void* d_out, int out_size, void* d_ws, size_t ws_size,
                              hipStream_t stream)
{
    (void)in_sizes; (void)n_in; (void)out_size; (void)ws_size;
    // 0=hidden_state (unused), 1=output_sequence, 2=emb_out, 3=W_dec,
    // 4=b_dec, 5=gamma, 6=beta, 7=W_voc, 8=b_voc
    const int*   seq  = (const int*)  d_in[1];
    const float* emb  = (const float*)d_in[2];
    const float* Wdec = (const float*)d_in[3];
    const float* bdec = (const float*)d_in[4];
    const float* gam  = (const float*)d_in[5];
    const float* bet  = (const float*)d_in[6];
    const float* Wvoc = (const float*)d_in[7];
    const float* bvoc = (const float*)d_in[8];

    float* out  = (float*)d_out;
    float* zout = out;            // B*E floats
    float* y    = out + B_ * E_;  // B*V floats

    // workspace layout: records (B*2*NH*REC f32) | flags (B*2*NH u64) | corr
    const size_t vbuf_bytes = (size_t)B_ * 2 * NH_ * REC_ * sizeof(float); // 196608
    const size_t flg_bytes  = (size_t)B_ * 2 * NH_ * sizeof(u64);          // 4096
    float* vbuf = (float*)d_ws;
    u64*   flg  = (u64*)((char*)d_ws + vbuf_bytes);
    float* corr = (float*)((char*)d_ws + vbuf_bytes + flg_bytes);

    // flags must not alias a previous replay's tags — zero them (4 KiB)
    hipMemsetAsync(flg, 0, flg_bytes, stream);

    hipLaunchKernelGGL(scan8w, dim3(B_ * NH_), dim3(1024), 0, stream,
                       seq, emb, Wdec, bdec, gam, bet, zout, vbuf, flg);
    hipLaunchKernelGGL(logits_k, dim3(V_ / 128), dim3(512), 0, stream,
                       zout, Wvoc, bvoc, y);
    hipLaunchKernelGGL(lse_k, dim3(B_), dim3(1024), 0, stream, y, corr);
    hipLaunchKernelGGL(fix_k, dim3(1000), dim3(256), 0, stream, y, corr);
}

// Round 4
// 4552.377 us; speedup vs baseline: 29.0670x; 29.0670x over previous
//
#include <hip/hip_runtime.h>
#include <math.h>

typedef float v4 __attribute__((ext_vector_type(4)));
typedef unsigned long long u64;

static constexpr int B_ = 32;
static constexpr int S_ = 2048;
static constexpr int E_ = 512;
static constexpr int V_ = 32000;
static constexpr float EPS_ = 1e-6f;
static constexpr int NH_ = 8;     // blocks (column slices) per batch
static constexpr int CH_ = 64;    // columns per block

// ---------------------------------------------------------------------------
// K1: 8-blocks-per-batch scan, 256 blocks x 1024 threads (1 block/CU).
// Round-0 proven skeleton (matvec mapping with 0 bank conflicts; per-element
// TAGGED u64 exchange via RELAXED agent atomics — no cache-maintenance ops,
// self-validating, replay-safe) with three surgical changes:
//  1) stats-in-publish: wave 0 butterflies (S,Q) of its slice AFTER the value
//     stores are in flight and publishes 2 extra tagged words. Post-B2 LN is
//     16 broadcast LDS reads + 14 adds (was: 12-op shfl chain + B3 + 16-sum).
//  2) early dedicated pollers: waves 9..15 (448 thr = the 448 foreign
//     elements) start polling right after B1, overlapping wave-0's
//     reduce+publish. Wave 8 lanes 0..15 poll foreign stat words.
//  3) barriers 4 -> 3 per step.
// Deadlock-free: polls are strictly after B1; publishes depend only on B1;
// max inter-block skew is one publish (opposite parity slot), so exact-match
// tags are never missed.
// ---------------------------------------------------------------------------
__global__ __launch_bounds__(1024) void scan8w(
    const int* __restrict__ seq,     // (B,S)
    const float* __restrict__ emb,   // (V,E)
    const float* __restrict__ Wdec,  // (E,E) row-major
    const float* __restrict__ bdec,  // (E)
    const float* __restrict__ gamma, // (E)
    const float* __restrict__ beta,  // (E)
    float* __restrict__ zout,        // (B,E)
    u64* __restrict__ zpub)          // values (B,2,E) + stats (B,2,2,8)
{
    __shared__ __align__(16) float zs[E_];        // z_in
    __shared__ __align__(16) float part[16][CH_]; // matvec partials
    __shared__ __align__(16) float zmbuf[E_];     // gathered zmid (all 512)
    __shared__ float sst[NH_][2];                 // per-slice (S,Q)
    __shared__ int   seq_l[S_];

    const int bid  = blockIdx.x;
    const int b    = bid & 31;    // batch
    const int h    = bid >> 5;    // slice 0..7
    const int c0   = h * CH_;
    const int tid  = threadIdx.x;
    const int wv   = tid >> 6;    // 16 waves
    const int lane = tid & 63;
    const int cg   = lane & 15;   // 4-col group
    const int sub  = lane >> 4;   // 8-row subchunk
    const int row0 = wv * 32 + sub * 8;

    // --- W slice into VGPRs (8 x v4 = 32 regs), pinned via asm ---
    v4 w[8];
    {
        const float* wp = Wdec + (size_t)row0 * E_ + c0 + 4 * cg;
        #pragma unroll
        for (int q = 0; q < 8; ++q) {
            const float* p = wp + (size_t)q * E_;
            asm volatile("global_load_dwordx4 %0, %1, off\n\ts_waitcnt vmcnt(0)"
                         : "=v"(w[q]) : "v"(p));
        }
    }

    const int* seqb = seq + (size_t)b * S_;
    for (int i = tid; i < S_; i += 1024) seq_l[i] = seqb[i];

    const float gmm = (tid < E_) ? gamma[tid] : 0.f;
    const float btt = (tid < E_) ? beta[tid] : 0.f;
    const float bdr = (tid < CH_) ? bdec[c0 + tid] : 0.f;
    const float sqrtE = sqrtf(512.0f);
    u64* zpb = zpub + (size_t)b * 2 * E_;                     // values
    u64* zst = zpub + (size_t)B_ * 2 * E_ + (size_t)b * 32;   // [p][k][8]

    // poller element for waves 9..15: the j-th foreign element
    int pe = 0;
    if (wv >= 9) { const int j = tid - 576; pe = j + ((j >= c0) ? CH_ : 0); }

    __syncthreads();
    if (tid < E_) zs[tid] = emb[(size_t)seq_l[0] * E_ + tid] * sqrtE;  // x_0
    __syncthreads();

    for (int t = 0; t < S_; ++t) {
        const int p = t & 1;
        const unsigned tag = (unsigned)(t + 1);

        // prefetch next embedding row (consumed at step end)
        const int tn = seq_l[(t + 1 < S_) ? t + 1 : t];
        float e = 0.f;
        if (tid < E_) e = emb[(size_t)tn * E_ + tid];

        // --- matvec: 8 rows x own 4 cols per thread (proven mapping) ---
        const v4 za = *(const v4*)&zs[row0];
        const v4 zb = *(const v4*)&zs[row0 + 4];
        v4 acc = za.x * w[0];
        acc += za.y * w[1];
        acc += za.z * w[2];
        acc += za.w * w[3];
        acc += zb.x * w[4];
        acc += zb.y * w[5];
        acc += zb.z * w[6];
        acc += zb.w * w[7];
        // reduce over sub (lanes cg, cg+16, cg+32, cg+48)
        acc.x += __shfl_down(acc.x, 16);
        acc.y += __shfl_down(acc.y, 16);
        acc.z += __shfl_down(acc.z, 16);
        acc.w += __shfl_down(acc.w, 16);
        acc.x += __shfl_down(acc.x, 32);
        acc.y += __shfl_down(acc.y, 32);
        acc.z += __shfl_down(acc.z, 32);
        acc.w += __shfl_down(acc.w, 32);
        if (lane < 16) *(v4*)&part[wv][4 * cg] = acc;
        __syncthreads();                                   // B1

        if (tid < CH_) {
            // --- wave 0: col-reduce, publish values, then stats ---
            float sum = part[0][tid];
            #pragma unroll
            for (int k = 1; k < 16; ++k) sum += part[k][tid];
            const float zmid = zs[c0 + tid] + sum + bdr;
            union { float f; unsigned u; } cv; cv.f = zmid;
            __hip_atomic_store(&zpb[p * E_ + c0 + tid],
                               ((u64)tag << 32) | cv.u,
                               __ATOMIC_RELAXED, __HIP_MEMORY_SCOPE_AGENT);
            zmbuf[c0 + tid] = zmid;            // own slice -> LDS
            // slice stats butterfly (overlaps value-store flight)
            float s = zmid, q2 = zmid * zmid;
            #pragma unroll
            for (int m = 1; m < 64; m <<= 1) {
                s  += __shfl_xor(s, m);
                q2 += __shfl_xor(q2, m);
            }
            if (tid == 0) {
                union { float f; unsigned u; } c1, c2; c1.f = s; c2.f = q2;
                __hip_atomic_store(&zst[p * 16 + 0 + h], ((u64)tag << 32) | c1.u,
                                   __ATOMIC_RELAXED, __HIP_MEMORY_SCOPE_AGENT);
                __hip_atomic_store(&zst[p * 16 + 8 + h], ((u64)tag << 32) | c2.u,
                                   __ATOMIC_RELAXED, __HIP_MEMORY_SCOPE_AGENT);
                sst[h][0] = s; sst[h][1] = q2;
            }
        } else if (wv == 8) {
            // --- wave 8 lanes 0..15: poll 14 foreign stat words ---
            if (lane < 16) {
                const int i = lane & 7, k = lane >> 3;
                if (i != h) {
                    const u64* ap = &zst[p * 16 + k * 8 + i];
                    u64 v;
                    do {
                        v = __hip_atomic_load(ap, __ATOMIC_RELAXED,
                                              __HIP_MEMORY_SCOPE_AGENT);
                    } while ((unsigned)(v >> 32) != tag);
                    union { unsigned u; float f; } cv; cv.u = (unsigned)v;
                    sst[i][k] = cv.f;
                }
            }
        } else if (wv >= 9) {
            // --- waves 9..15: poll foreign values (start immediately) ---
            const u64* ap = &zpb[p * E_ + pe];
            u64 v;
            do {
                v = __hip_atomic_load(ap, __ATOMIC_RELAXED,
                                      __HIP_MEMORY_SCOPE_AGENT);
            } while ((unsigned)(v >> 32) != tag);
            union { unsigned u; float f; } cv; cv.u = (unsigned)v;
            zmbuf[pe] = cv.f;
        }
        __syncthreads();                                   // B2

        if (tid < E_) {
            // LN from broadcast LDS stats (fixed order -> identical in all
            // 8 replica blocks of this batch)
            const float St =
                ((sst[0][0] + sst[1][0]) + (sst[2][0] + sst[3][0]))
              + ((sst[4][0] + sst[5][0]) + (sst[6][0] + sst[7][0]));
            const float Qt =
                ((sst[0][1] + sst[1][1]) + (sst[2][1] + sst[3][1]))
              + ((sst[4][1] + sst[5][1]) + (sst[6][1] + sst[7][1]));
            const float mu   = St * (1.0f / E_);
            const float var  = (Qt - St * mu) * (1.0f / (E_ - 1));
            const float invd = 1.0f / (sqrtf(var) + EPS_);
            const float zl   = gmm * (zmbuf[tid] - mu) * invd + btt;
            if (t == S_ - 1) {
                if (h == 0) zout[(size_t)b * E_ + tid] = zl;
            } else {
                zs[tid] = fmaf(e, sqrtE, zl);
            }
        }
        __syncthreads();                                   // B3
    }
}

// ---------------------------------------------------------------------------
// K2: y = z @ W_voc + b_voc. 250 blocks x 512 threads; each thread owns one
// vocab column for 8 batches (bg group). z reads are thread-uniform ->
// scalar-cache loads; W_voc streamed once (same cols across bg reuse L1).
// ---------------------------------------------------------------------------
__global__ __launch_bounds__(512) void logits_k(
    const float* __restrict__ zfin,  // (B,E)
    const float* __restrict__ Wvoc,  // (E,V)
    const float* __restrict__ bvoc,  // (V)
    float* __restrict__ y)           // (B,V)
{
    const int tid = threadIdx.x;
    const int col = blockIdx.x * 128 + (tid & 127);
    const int bg  = (tid >> 7) * 8;           // 0,8,16,24

    float acc[8] = {0.f, 0.f, 0.f, 0.f, 0.f, 0.f, 0.f, 0.f};
    const float* wp = Wvoc + col;
    const float* zp = zfin + (size_t)bg * E_;

    for (int k = 0; k < E_; k += 4) {
        const float w0 = wp[(size_t)(k + 0) * V_];
        const float w1 = wp[(size_t)(k + 1) * V_];
        const float w2 = wp[(size_t)(k + 2) * V_];
        const float w3 = wp[(size_t)(k + 3) * V_];
        #pragma unroll
        for (int g = 0; g < 8; ++g) {
            acc[g] = fmaf(zp[g * E_ + k + 0], w0, acc[g]);
            acc[g] = fmaf(zp[g * E_ + k + 1], w1, acc[g]);
            acc[g] = fmaf(zp[g * E_ + k + 2], w2, acc[g]);
            acc[g] = fmaf(zp[g * E_ + k + 3], w3, acc[g]);
        }
    }
    const float bv = bvoc[col];
    #pragma unroll
    for (int g = 0; g < 8; ++g)
        y[(size_t)(bg + g) * V_ + col] = acc[g] + bv;
}

// ---------------------------------------------------------------------------
// K3: per-batch log-sum-exp (bias already folded into y)
// ---------------------------------------------------------------------------
__global__ __launch_bounds__(1024) void lse_k(
    const float* __restrict__ y, float* __restrict__ corr)
{
    __shared__ float redm[16], redl[16];
    const int b = blockIdx.x;
    const int tid = threadIdx.x;
    const float* row = y + (size_t)b * V_;

    float m = -3.0e38f, l = 0.f;
    for (int v = tid; v < V_; v += 1024) {
        const float x = row[v];
        const float nm = fmaxf(m, x);
        l = l * __expf(m - nm) + __expf(x - nm);
        m = nm;
    }
    #pragma unroll
    for (int off = 32; off > 0; off >>= 1) {
        const float om = __shfl_down(m, off);
        const float ol = __shfl_down(l, off);
        const float nm = fmaxf(m, om);
        l = l * __expf(m - nm) + ol * __expf(om - nm);
        m = nm;
    }
    const int lane = tid & 63, wvv = tid >> 6;
    if (lane == 0) { redm[wvv] = m; redl[wvv] = l; }
    __syncthreads();
    if (tid == 0) {
        float M = redm[0], L = redl[0];
        for (int k = 1; k < 16; ++k) {
            const float nm = fmaxf(M, redm[k]);
            L = L * __expf(M - nm) + redl[k] * __expf(redm[k] - nm);
            M = nm;
        }
        corr[b] = M + logf(L);
    }
}

// ---------------------------------------------------------------------------
// K4: y -= corr[b]
// ---------------------------------------------------------------------------
__global__ __launch_bounds__(256) void fix_k(
    float* __restrict__ y, const float* __restrict__ corr)
{
    const int idx = blockIdx.x * 256 + threadIdx.x;   // float4 index
    const size_t o = (size_t)idx * 4;
    const int b = (int)(o / V_);
    const float cr = corr[b];
    v4 v = *(v4*)(y + o);
    v = v - cr;
    *(v4*)(y + o) = v;
}

// ---------------------------------------------------------------------------
extern "C" void kernel_launch(void* const* d_in, const int* in_sizes, int n_in,
                              void* d_out, int out_size, void* d_ws, size_t ws_size,
                              hipStream_t stream)
{
    (void)in_sizes; (void)n_in; (void)out_size; (void)ws_size;
    // 0=hidden_state (unused), 1=output_sequence, 2=emb_out, 3=W_dec,
    // 4=b_dec, 5=gamma, 6=beta, 7=W_voc, 8=b_voc
    const int*   seq  = (const int*)  d_in[1];
    const float* emb  = (const float*)d_in[2];
    const float* Wdec = (const float*)d_in[3];
    const float* bdec = (const float*)d_in[4];
    const float* gam  = (const float*)d_in[5];
    const float* bet  = (const float*)d_in[6];
    const float* Wvoc = (const float*)d_in[7];
    const float* bvoc = (const float*)d_in[8];

    float* out  = (float*)d_out;
    float* zout = out;            // B*E floats
    float* y    = out + B_ * E_;  // B*V floats

    // workspace: values (B*2*E u64) + stats (B*2*2*8 u64) + corr
    const size_t exch_u64 = (size_t)B_ * 2 * E_ + (size_t)B_ * 32;
    u64*   zpub = (u64*)d_ws;
    float* corr = (float*)((char*)d_ws + exch_u64 * sizeof(u64)); // B floats

    // tags must not alias t+1 from a previous replay — zero the exchange buf
    hipMemsetAsync(zpub, 0, exch_u64 * sizeof(u64), stream);

    hipLaunchKernelGGL(scan8w, dim3(B_ * NH_), dim3(1024), 0, stream,
                       seq, emb, Wdec, bdec, gam, bet, zout, zpub);
    hipLaunchKernelGGL(logits_k, dim3(V_ / 128), dim3(512), 0, stream,
                       zout, Wvoc, bvoc, y);
    hipLaunchKernelGGL(lse_k, dim3(B_), dim3(1024), 0, stream, y, corr);
    hipLaunchKernelGGL(fix_k, dim3(1000), dim3(256), 0, stream, y, corr);
}